// Round 1
// baseline (126.694 us; speedup 1.0000x reference)
//
#include <hip/hip_runtime.h>

// Problem constants (from reference)
#define BB   4
#define N1   1024
#define DIM  1024
#define FF   4
#define NN   1025           // N1 + 1
#define NTOT (FF * NN)      // 4100
#define SIM_TOTAL ((size_t)BB * N1 * NTOT)
#define NEGV (-1e9f)

__device__ __forceinline__ float wave_reduce_sum(float v) {
#pragma unroll
    for (int off = 32; off > 0; off >>= 1)
        v += __shfl_down(v, off, 64);
    return v;
}

// One block (256 threads) per output row (b, i).
//  - load lhs row (1024 f32) as float4, accumulate |l|^2 partial
//  - for each f in 0..3: load rhs row (b, f*N + i + 1), accumulate dot & |r|^2
//  - fill the row's 4100 outputs with -1e9 (1025 float4 stores)
//  - block-reduce 9 scalars, thread 0 writes 4 kept sims + lhs_norm
__global__ __launch_bounds__(256)
void lcs_kernel(const float* __restrict__ lhs,
                const float* __restrict__ rhs,
                float* __restrict__ out) {
    const int row = blockIdx.x;        // 0 .. B*N1-1
    const int b   = row >> 10;         // / N1
    const int i   = row & (N1 - 1);    // % N1
    const int tid = threadIdx.x;

    // ---- lhs row load (256 threads x float4 = 1024 floats) ----
    const float4* lrow = (const float4*)(lhs + (size_t)row * DIM);
    const float4 lv = lrow[tid];
    float p_l2 = lv.x * lv.x + lv.y * lv.y + lv.z * lv.z + lv.w * lv.w;

    // ---- rhs rows: f*N + i + 1 for f in 0..3 ----
    float p_dot[FF], p_r2[FF];
#pragma unroll
    for (int f = 0; f < FF; ++f) {
        const size_t rrow_idx = (size_t)b * NTOT + (size_t)f * NN + (i + 1);
        const float4* rrow = (const float4*)(rhs + rrow_idx * DIM);
        const float4 rv = rrow[tid];
        p_dot[f] = lv.x * rv.x + lv.y * rv.y + lv.z * rv.z + lv.w * rv.w;
        p_r2[f]  = rv.x * rv.x + rv.y * rv.y + rv.z * rv.z + rv.w * rv.w;
    }

    // ---- fill this row's outputs with -1e9 ----
    // Row pitch = 4100 floats = 16400 bytes = 1025 float4 -> 16B aligned.
    float4* orow4 = (float4*)(out + (size_t)row * NTOT);
    const float4 negv = make_float4(NEGV, NEGV, NEGV, NEGV);
#pragma unroll
    for (int k = tid; k < NTOT / 4; k += 256)
        orow4[k] = negv;

    // ---- block reduction of 9 scalars ----
    float vals[9];
    vals[0] = p_l2;
#pragma unroll
    for (int f = 0; f < FF; ++f) {
        vals[1 + 2 * f] = p_dot[f];
        vals[2 + 2 * f] = p_r2[f];
    }

    __shared__ float red[4][9];
    const int wave = tid >> 6;
    const int lane = tid & 63;
#pragma unroll
    for (int q = 0; q < 9; ++q) {
        const float r = wave_reduce_sum(vals[q]);
        if (lane == 0) red[wave][q] = r;
    }
    __syncthreads();   // orders fill stores before thread 0's scatter, too

    if (tid == 0) {
        float s[9];
#pragma unroll
        for (int q = 0; q < 9; ++q)
            s[q] = red[0][q] + red[1][q] + red[2][q] + red[3][q];

        const float l2 = s[0];
        float* orow = out + (size_t)row * NTOT;
#pragma unroll
        for (int f = 0; f < FF; ++f) {
            const float dot = s[1 + 2 * f];
            const float r2  = s[2 + 2 * f];
            orow[f * NN + i + 1] = (dot * dot) / (l2 * r2);
        }
        out[SIM_TOTAL + row] = sqrtf(l2);   // lhs_norm (B, N1, 1)
    }
}

extern "C" void kernel_launch(void* const* d_in, const int* in_sizes, int n_in,
                              void* d_out, int out_size, void* d_ws, size_t ws_size,
                              hipStream_t stream) {
    const float* lhs = (const float*)d_in[0];  // (B, N1, DIM)
    const float* rhs = (const float*)d_in[1];  // (B, NTOT, DIM)
    float* out = (float*)d_out;                // sim (B,N1,NTOT) ++ lhs_norm (B,N1,1)

    lcs_kernel<<<BB * N1, 256, 0, stream>>>(lhs, rhs, out);
}